// Round 4
// baseline (702.201 us; speedup 1.0000x reference)
//
#include <hip/hip_runtime.h>
#include <cstddef>
#include <cstdint>

// Problem constants
constexpr int B  = 8;
constexpr int L  = 1024;
constexpr int D  = 768;
constexpr int DI = 1536;
constexpr int DS = 16;
constexpr int NL = 2;
constexpr float DECAY   = 0.9f;
constexpr float INSCALE = 0.1f;
constexpr float LN_EPS  = 1e-5f;

typedef __attribute__((ext_vector_type(8))) short bf16x8;
typedef __attribute__((ext_vector_type(4))) float f32x4;

typedef __attribute__((address_space(3))) uint32_t       lds_u32;
typedef const __attribute__((address_space(1))) uint32_t glb_u32;

__device__ __forceinline__ float siluf(float v) { return v / (1.0f + expf(-v)); }

// f32 -> bf16 (round to nearest even)
__device__ __forceinline__ short f2bf(float f) {
  uint32_t u = __float_as_uint(f);
  u += 0x7fff + ((u >> 16) & 1);
  return (short)(u >> 16);
}
__device__ __forceinline__ float bf2f(short s) {
  return __uint_as_float(((uint32_t)(uint16_t)s) << 16);
}

__device__ __forceinline__ void load_lds16(const short* g, short* l) {
  __builtin_amdgcn_global_load_lds((glb_u32*)g, (lds_u32*)l, 16, 0, 0);
}

// ---------------- convert input x: f32 copy + bf16 copy ----------------
__global__ void convert_x_kernel(const float* __restrict__ x, float* __restrict__ xf,
                                 short* __restrict__ xb, int n4) {
  int i = blockIdx.x * blockDim.x + threadIdx.x;
  if (i >= n4) return;
  float4 v = ((const float4*)x)[i];
  ((float4*)xf)[i] = v;
  short4 s;
  s.x = f2bf(v.x); s.y = f2bf(v.y); s.z = f2bf(v.z); s.w = f2bf(v.w);
  ((short4*)xb)[i] = s;
}

// ---------------- all weight transposes in one launch ----------------
// Wi[l]: [768,3072] -> Wt_i[l]: [3072,768];  Wo[l]: [1536,768] -> Wt_o[l]: [768,1536]
__global__ __launch_bounds__(256) void transpose_all_kernel(const float* __restrict__ Wi,
                                                            const float* __restrict__ Wo,
                                                            short* __restrict__ Wt_i,
                                                            short* __restrict__ Wt_o) {
  __shared__ float t[32][33];
  const int layer = blockIdx.y;
  int bid = blockIdx.x;
  const float* W; short* Wt; int K, N, bx, by;
  if (bid < 2304) {           // Wi tiles: 96 x, 24 y
    W  = Wi  + (size_t)layer * D * 2 * DI;
    Wt = Wt_i + (size_t)layer * 2 * DI * D;
    K = D; N = 2 * DI; bx = bid % 96; by = bid / 96;
  } else {                    // Wo tiles: 24 x, 48 y
    bid -= 2304;
    W  = Wo  + (size_t)layer * DI * D;
    Wt = Wt_o + (size_t)layer * D * DI;
    K = DI; N = D; bx = bid % 24; by = bid / 24;
  }
  const int n0 = bx * 32, k0 = by * 32;
  const int tx = threadIdx.x & 31, ty = threadIdx.x >> 5;
#pragma unroll
  for (int r = ty; r < 32; r += 8) t[r][tx] = W[(size_t)(k0 + r) * N + n0 + tx];
  __syncthreads();
#pragma unroll
  for (int r = ty; r < 32; r += 8) Wt[(size_t)(n0 + r) * K + k0 + tx] = f2bf(t[tx][r]);
}

// ---------------- bf16 MFMA GEMM, double-buffered with counted vmcnt ----------------
// C[M,N] = A[M,K] @ Bt[N,K]^T.
// MODE 0: split output — cols < DI -> f32 Pf[row*DI+col]; cols >= DI -> bf16 Pb[row*DI+col-DI]
// MODE 1: f32 accumulate into Pf[row*N+col] and write bf16 copy to Pb[row*N+col]
template<int MODE>
__global__ __launch_bounds__(256) void gemm_bt(const short* __restrict__ A,
                                               const short* __restrict__ Bt,
                                               float* __restrict__ Pf,
                                               short* __restrict__ Pb,
                                               int M, int N, int K) {
  __shared__ short As[2][128 * 32];
  __shared__ short Bs[2][128 * 32];
  const int tid  = threadIdx.x;
  const int lane = tid & 63;
  const int w    = tid >> 6;
  const int wm   = w >> 1;
  const int wn   = w & 1;
  const int bm   = blockIdx.y * 128;
  const int bn   = blockIdx.x * 128;

  const int seg0 = w * 2;
  const int rS0  = seg0 * 16 + (lane >> 2);
  const int kc   = (lane & 3) * 8;

  const short* gA0 = A  + (size_t)(bm + rS0) * K + kc;
  const short* gA1 = gA0 + (size_t)16 * K;
  const short* gB0 = Bt + (size_t)(bn + rS0) * K + kc;
  const short* gB1 = gB0 + (size_t)16 * K;

  f32x4 acc[4][4];
#pragma unroll
  for (int i = 0; i < 4; ++i)
#pragma unroll
    for (int j = 0; j < 4; ++j) acc[i][j] = (f32x4)(0.f);

  const int fr = lane & 15;
  const int fk = (lane >> 4) * 8;
  const int NT = K / 32;

  auto stage = [&](int bi, int k0) {
    load_lds16(gA0 + k0, &As[bi][(size_t)seg0 * 512]);
    load_lds16(gA1 + k0, &As[bi][(size_t)(seg0 + 1) * 512]);
    load_lds16(gB0 + k0, &Bs[bi][(size_t)seg0 * 512]);
    load_lds16(gB1 + k0, &Bs[bi][(size_t)(seg0 + 1) * 512]);
  };
  auto compute = [&](int bi) {
    bf16x8 af[4], bfr[4];
#pragma unroll
    for (int i = 0; i < 4; ++i)
      af[i] = *(const bf16x8*)&As[bi][(size_t)(wm * 64 + i * 16 + fr) * 32 + fk];
#pragma unroll
    for (int j = 0; j < 4; ++j)
      bfr[j] = *(const bf16x8*)&Bs[bi][(size_t)(wn * 64 + j * 16 + fr) * 32 + fk];
#pragma unroll
    for (int i = 0; i < 4; ++i)
#pragma unroll
      for (int j = 0; j < 4; ++j)
        acc[i][j] = __builtin_amdgcn_mfma_f32_16x16x32_bf16(af[i], bfr[j], acc[i][j], 0, 0, 0);
  };

  // prologue: stage tile 0, full drain
  stage(0, 0);
  asm volatile("s_waitcnt vmcnt(0)" ::: "memory");
  __builtin_amdgcn_s_barrier();
  asm volatile("" ::: "memory");

  // steady state: next tile's loads stay in flight under compute
  for (int t = 0; t < NT - 1; ++t) {
    stage((t + 1) & 1, (t + 1) * 32);
    asm volatile("s_waitcnt vmcnt(4)" ::: "memory");   // tile t fully landed (mine)
    __builtin_amdgcn_s_barrier();                      // ... and everyone else's
    asm volatile("" ::: "memory");
    compute(t & 1);
    asm volatile("" ::: "memory");
    __builtin_amdgcn_s_barrier();                      // all reads done; buffer reusable
    asm volatile("" ::: "memory");
  }
  // last tile
  asm volatile("s_waitcnt vmcnt(0)" ::: "memory");
  __builtin_amdgcn_s_barrier();
  asm volatile("" ::: "memory");
  compute((NT - 1) & 1);

  // epilogue: C/D frag mapping col=lane&15, row=(lane>>4)*4+r
  const int orow = (lane >> 4) * 4;
  const int ocol = lane & 15;
#pragma unroll
  for (int i = 0; i < 4; ++i) {
#pragma unroll
    for (int r = 0; r < 4; ++r) {
      const size_t row = (size_t)(bm + wm * 64 + i * 16 + orow + r);
#pragma unroll
      for (int j = 0; j < 4; ++j) {
        const int col = bn + wn * 64 + j * 16 + ocol;
        float v = acc[i][j][r];
        if (MODE == 0) {
          if (bn < DI) Pf[row * DI + col] = v;
          else         Pb[row * DI + col - DI] = f2bf(v);
        } else {
          float o = Pf[row * N + col] + v;
          Pf[row * N + col] = o;
          Pb[row * N + col] = f2bf(o);
        }
      }
    }
  }
}

// ---------------- fused causal dwconv(DC=4)+SiLU -> u reduction ----------------
// One block per l. Conv output (8x1536 f32) lives only in LDS.
// u[l,b,s] = INSCALE * sum_c silu(conv(xin))[b,c] * A[l,c,s]
__global__ __launch_bounds__(256) void conv_u_kernel(const float* __restrict__ xin,  // [B*L, DI]
                                                     const float* __restrict__ cw,   // [DI,4]
                                                     const float* __restrict__ cb,   // [DI]
                                                     const float* __restrict__ A_l,  // [L,DI,DS]
                                                     float* __restrict__ u) {        // [L,B*DS]
  const int l = blockIdx.x;
  __shared__ float smem[B * DI];  // 48 KB: conv output, then reused as reduction buf

  for (int i = threadIdx.x; i < B * (DI / 4); i += 256) {
    const int b = i / (DI / 4);
    const int c = (i % (DI / 4)) * 4;
    float4 q0 = *(const float4*)&cw[(c + 0) * 4];
    float4 q1 = *(const float4*)&cw[(c + 1) * 4];
    float4 q2 = *(const float4*)&cw[(c + 2) * 4];
    float4 q3 = *(const float4*)&cw[(c + 3) * 4];
    float4 acc = *(const float4*)&cb[c];
    const float* xp = xin + (size_t)b * L * DI + c;
#pragma unroll
    for (int k = 0; k < 4; ++k) {
      int lk = l - 3 + k;
      if (lk >= 0) {
        float4 xv = *(const float4*)&xp[(size_t)lk * DI];
        acc.x += (&q0.x)[k] * xv.x;
        acc.y += (&q1.x)[k] * xv.y;
        acc.z += (&q2.x)[k] * xv.z;
        acc.w += (&q3.x)[k] * xv.w;
      }
    }
    acc.x = siluf(acc.x); acc.y = siluf(acc.y);
    acc.z = siluf(acc.z); acc.w = siluf(acc.w);
    *(float4*)&smem[b * DI + c] = acc;
  }
  __syncthreads();

  const int s4 = threadIdx.x & 3;    // s quarter
  const int cg = threadIdx.x >> 2;   // 0..63
  const float* Ap = A_l + (size_t)l * DI * DS + s4 * 4;

  float4 acc[B];
#pragma unroll
  for (int b = 0; b < B; ++b) acc[b] = make_float4(0.f, 0.f, 0.f, 0.f);

#pragma unroll 4
  for (int c0 = 0; c0 < DI; c0 += 64) {
    const int c = c0 + cg;
    float4 a4 = *(const float4*)&Ap[(size_t)c * DS];
#pragma unroll
    for (int b = 0; b < B; ++b) {
      float xv = smem[b * DI + c];
      acc[b].x += xv * a4.x; acc[b].y += xv * a4.y;
      acc[b].z += xv * a4.z; acc[b].w += xv * a4.w;
    }
  }

  __syncthreads();  // conv staging fully consumed; reuse smem as red[128][65]
  float* red = smem;
#pragma unroll
  for (int b = 0; b < B; ++b) {
#pragma unroll
    for (int j = 0; j < 4; ++j) {
      int o = b * 16 + s4 * 4 + j;
      red[o * 65 + cg] = (&acc[b].x)[j];
    }
  }
  __syncthreads();
  if (threadIdx.x < 128) {
    const int o = threadIdx.x;
    float sum = 0.f;
#pragma unroll 8
    for (int g = 0; g < 64; ++g) sum += red[o * 65 + g];
    u[(size_t)l * (B * DS) + o] = INSCALE * sum;
  }
}

// ---------------- truncated-lookback scan ----------------
constexpr int SCAN_CH = 64;
constexpr int SCAN_W  = 320;   // 0.9^320 ~ 2e-15: exact to f32 precision
__global__ void scan_kernel(const float* __restrict__ u, float* __restrict__ hs) {
  const int t  = threadIdx.x;              // 0..127
  const int l1 = blockIdx.x * SCAN_CH;
  int l0 = l1 - SCAN_W; if (l0 < 0) l0 = 0;
  float h = 0.f;
  for (int l = l0; l < l1; ++l)
    h = DECAY * h + u[(size_t)l * (B * DS) + t];
#pragma unroll 4
  for (int l = l1; l < l1 + SCAN_CH; ++l) {
    h = DECAY * h + u[(size_t)l * (B * DS) + t];
    hs[(size_t)l * (B * DS) + t] = h;
  }
}

// ---------------- y[b,l,c] = (sum_s hs[l,b,s]*Bm[l,s,c]) * silu(z), bf16 z in, bf16 y out ----
__global__ __launch_bounds__(128) void xssm_kernel(const float* __restrict__ hs,   // [L,B*DS]
                                                   const float* __restrict__ B_l,  // [L,DS,DI]
                                                   const short* __restrict__ zb,   // [B*L,DI] bf16
                                                   short* __restrict__ y) {        // [B*L,DI] bf16
  const int l = blockIdx.x;
  const int c = (blockIdx.y * 128 + threadIdx.x) * 4;
  __shared__ float hsl[B * DS];
  if (threadIdx.x < B * DS) hsl[threadIdx.x] = hs[(size_t)l * (B * DS) + threadIdx.x];
  __syncthreads();
  const float* Bp = B_l + (size_t)l * DS * DI + c;

  float4 acc[B];
#pragma unroll
  for (int b = 0; b < B; ++b) acc[b] = make_float4(0.f, 0.f, 0.f, 0.f);
#pragma unroll
  for (int s = 0; s < DS; ++s) {
    float4 bv = *(const float4*)&Bp[(size_t)s * DI];
#pragma unroll
    for (int b = 0; b < B; ++b) {
      float h = hsl[b * DS + s];
      acc[b].x += h * bv.x; acc[b].y += h * bv.y;
      acc[b].z += h * bv.z; acc[b].w += h * bv.w;
    }
  }
#pragma unroll
  for (int b = 0; b < B; ++b) {
    short4 zs = *(const short4*)&zb[((size_t)b * L + l) * DI + c];
    short4 o;
    o.x = f2bf(acc[b].x * siluf(bf2f(zs.x)));
    o.y = f2bf(acc[b].y * siluf(bf2f(zs.y)));
    o.z = f2bf(acc[b].z * siluf(bf2f(zs.z)));
    o.w = f2bf(acc[b].w * siluf(bf2f(zs.w)));
    *(short4*)&y[((size_t)b * L + l) * DI + c] = o;
  }
}

// ---------------- LayerNorm over D ----------------
__global__ __launch_bounds__(256) void ln_kernel(const float* __restrict__ x,
                                                 const float* __restrict__ gam,
                                                 const float* __restrict__ bet,
                                                 float* __restrict__ out) {
  const int row = blockIdx.x;
  const int t = threadIdx.x;
  const float* xr = x + (size_t)row * D;
  float v0 = xr[t], v1 = xr[t + 256], v2 = xr[t + 512];
  float s = v0 + v1 + v2;
  __shared__ float red[4], red2[4];
  const int wid = t >> 6, lane = t & 63;
#pragma unroll
  for (int off = 32; off > 0; off >>= 1) s += __shfl_down(s, off, 64);
  if (lane == 0) red[wid] = s;
  __syncthreads();
  float mu = (red[0] + red[1] + red[2] + red[3]) * (1.0f / D);
  float d0 = v0 - mu, d1 = v1 - mu, d2 = v2 - mu;
  float q = d0 * d0 + d1 * d1 + d2 * d2;
#pragma unroll
  for (int off = 32; off > 0; off >>= 1) q += __shfl_down(q, off, 64);
  if (lane == 0) red2[wid] = q;
  __syncthreads();
  float var = (red2[0] + red2[1] + red2[2] + red2[3]) * (1.0f / D);
  float rstd = rsqrtf(var + LN_EPS);
  size_t base = (size_t)row * D;
  out[base + t]       = d0 * rstd * gam[t]       + bet[t];
  out[base + t + 256] = d1 * rstd * gam[t + 256] + bet[t + 256];
  out[base + t + 512] = d2 * rstd * gam[t + 512] + bet[t + 512];
}

extern "C" void kernel_launch(void* const* d_in, const int* in_sizes, int n_in,
                              void* d_out, int out_size, void* d_ws, size_t ws_size,
                              hipStream_t stream) {
  (void)in_sizes; (void)n_in; (void)out_size; (void)ws_size;
  const float* x   = (const float*)d_in[0];
  const float* Wi  = (const float*)d_in[1];
  const float* cw  = (const float*)d_in[2];
  const float* cb  = (const float*)d_in[3];
  const float* Wo  = (const float*)d_in[4];
  const float* gam = (const float*)d_in[5];
  const float* bet = (const float*)d_in[6];
  const float* Am  = (const float*)d_in[7];
  const float* Bm  = (const float*)d_in[8];
  float* out = (float*)d_out;

  const size_t MN = (size_t)B * L;  // 8192

  float* buf_x  = (float*)d_ws;                          // [MN, D] f32 residual
  short* buf_xb = (short*)(buf_x + MN * D);              // [MN, D] bf16
  float* xin    = (float*)(buf_xb + MN * D);             // [MN, DI] f32 (conv input)
  short* zb     = (short*)(xin + MN * DI);               // [MN, DI] bf16 (gate)
  short* y_bf   = zb + MN * DI;                          // [MN, DI] bf16
  float* buf_u  = (float*)(y_bf + MN * DI);              // [L, B*DS]
  float* buf_hs = buf_u + (size_t)L * B * DS;            // [L, B*DS]
  short* Wt_i   = (short*)(buf_hs + (size_t)L * B * DS); // [NL, 2*DI, D] bf16
  short* Wt_o   = Wt_i + (size_t)NL * 2 * DI * D;        // [NL, D, DI]  bf16

  {
    int n4 = (int)(MN * D / 4);
    convert_x_kernel<<<(n4 + 255) / 256, 256, 0, stream>>>(x, buf_x, buf_xb, n4);
  }
  transpose_all_kernel<<<dim3(3456, NL), 256, 0, stream>>>(Wi, Wo, Wt_i, Wt_o);

  for (int layer = 0; layer < NL; ++layer) {
    const float* cw_l = cw + (size_t)layer * DI * 4;
    const float* cb_l = cb + (size_t)layer * DI;
    const float* A_l  = Am + (size_t)layer * L * DI * DS;
    const float* B_l  = Bm + (size_t)layer * L * DS * DI;
    const short* Wti_l = Wt_i + (size_t)layer * 2 * DI * D;
    const short* Wto_l = Wt_o + (size_t)layer * D * DI;

    // xz = x @ Wi: x_in half -> f32 xin, z half -> bf16 zb
    gemm_bt<0><<<dim3(2 * DI / 128, MN / 128), 256, 0, stream>>>(
        buf_xb, Wti_l, xin, zb, (int)MN, 2 * DI, D);

    // u = 0.1 * silu(dwconv(xin)) @ A_l   (conv output lives in LDS only)
    conv_u_kernel<<<L, 256, 0, stream>>>(xin, cw_l, cb_l, A_l, buf_u);

    // hs = scan(u)
    scan_kernel<<<L / SCAN_CH, B * DS, 0, stream>>>(buf_u, buf_hs);

    // y = (hs @ B_l) * silu(z)  -> bf16
    xssm_kernel<<<dim3(L, 3), 128, 0, stream>>>(buf_hs, B_l, zb, y_bf);

    // x += y @ Wo; also emit bf16 x for next layer
    gemm_bt<1><<<dim3(D / 128, MN / 128), 256, 0, stream>>>(
        y_bf, Wto_l, buf_x, buf_xb, (int)MN, D, DI);
  }

  ln_kernel<<<(int)MN, 256, 0, stream>>>(buf_x, gam, bet, out);
}

// Round 5
// 679.744 us; speedup vs baseline: 1.0330x; 1.0330x over previous
//
#include <hip/hip_runtime.h>
#include <cstddef>
#include <cstdint>

// Problem constants
constexpr int B  = 8;
constexpr int L  = 1024;
constexpr int D  = 768;
constexpr int DI = 1536;
constexpr int DS = 16;
constexpr int NL = 2;
constexpr float DECAY   = 0.9f;
constexpr float INSCALE = 0.1f;
constexpr float LN_EPS  = 1e-5f;

typedef __attribute__((ext_vector_type(8))) short bf16x8;
typedef __attribute__((ext_vector_type(4))) float f32x4;

typedef __attribute__((address_space(3))) uint32_t       lds_u32;
typedef const __attribute__((address_space(1))) uint32_t glb_u32;

__device__ __forceinline__ float siluf(float v) { return v / (1.0f + expf(-v)); }

// f32 -> bf16 (round to nearest even)
__device__ __forceinline__ short f2bf(float f) {
  uint32_t u = __float_as_uint(f);
  u += 0x7fff + ((u >> 16) & 1);
  return (short)(u >> 16);
}
__device__ __forceinline__ float bf2f(short s) {
  return __uint_as_float(((uint32_t)(uint16_t)s) << 16);
}

__device__ __forceinline__ void load_lds16(const short* g, short* l) {
  __builtin_amdgcn_global_load_lds((glb_u32*)g, (lds_u32*)l, 16, 0, 0);
}

// ---------------- convert input x: f32 copy + bf16 copy ----------------
__global__ void convert_x_kernel(const float* __restrict__ x, float* __restrict__ xf,
                                 short* __restrict__ xb, int n4) {
  int i = blockIdx.x * blockDim.x + threadIdx.x;
  if (i >= n4) return;
  float4 v = ((const float4*)x)[i];
  ((float4*)xf)[i] = v;
  short4 s;
  s.x = f2bf(v.x); s.y = f2bf(v.y); s.z = f2bf(v.z); s.w = f2bf(v.w);
  ((short4*)xb)[i] = s;
}

// ---------------- all weight transposes in one launch ----------------
__global__ __launch_bounds__(256) void transpose_all_kernel(const float* __restrict__ Wi,
                                                            const float* __restrict__ Wo,
                                                            short* __restrict__ Wt_i,
                                                            short* __restrict__ Wt_o) {
  __shared__ float t[32][33];
  const int layer = blockIdx.y;
  int bid = blockIdx.x;
  const float* W; short* Wt; int K, N, bx, by;
  if (bid < 2304) {           // Wi tiles: 96 x, 24 y
    W  = Wi  + (size_t)layer * D * 2 * DI;
    Wt = Wt_i + (size_t)layer * 2 * DI * D;
    K = D; N = 2 * DI; bx = bid % 96; by = bid / 96;
  } else {                    // Wo tiles: 24 x, 48 y
    bid -= 2304;
    W  = Wo  + (size_t)layer * DI * D;
    Wt = Wt_o + (size_t)layer * D * DI;
    K = DI; N = D; bx = bid % 24; by = bid / 24;
  }
  const int n0 = bx * 32, k0 = by * 32;
  const int tx = threadIdx.x & 31, ty = threadIdx.x >> 5;
#pragma unroll
  for (int r = ty; r < 32; r += 8) t[r][tx] = W[(size_t)(k0 + r) * N + n0 + tx];
  __syncthreads();
#pragma unroll
  for (int r = ty; r < 32; r += 8) Wt[(size_t)(n0 + r) * K + k0 + tx] = f2bf(t[tx][r]);
}

// ---------------- bf16 MFMA GEMM: C[M,N] = A[M,K] @ Bt[N,K]^T ----------------
// 3-buffer (BK=32) pipeline, prefetch depth 2, ONE barrier + ONE counted vmcnt
// per K-step (vmcnt(4): next tile landed, tile-after-next still in flight).
// MODE 0: col <  DI -> bf16 Pb[row*DI+col]        (x_in)
//         col >= DI -> bf16 Pb[M*DI + row*DI+col-DI] (z)
// MODE 1: f32 accumulate into Pf[row*N+col], bf16 copy to Pb[row*N+col]
template<int MODE>
__global__ __launch_bounds__(256) void gemm_bt(const short* __restrict__ A,
                                               const short* __restrict__ Bt,
                                               float* __restrict__ Pf,
                                               short* __restrict__ Pb,
                                               int M, int N, int K) {
  __shared__ short As[3][128 * 32];   // 3 x 8 KB
  __shared__ short Bs[3][128 * 32];   // 3 x 8 KB  (48 KB total)
  const int tid  = threadIdx.x;
  const int lane = tid & 63;
  const int w    = tid >> 6;
  const int wm   = w >> 1;
  const int wn   = w & 1;
  const int bm   = blockIdx.y * 128;
  const int bn   = blockIdx.x * 128;

  const int seg0 = w * 2;
  const int rS0  = seg0 * 16 + (lane >> 2);
  const int kc   = (lane & 3) * 8;

  const short* gA0 = A  + (size_t)(bm + rS0) * K + kc;
  const short* gA1 = gA0 + (size_t)16 * K;
  const short* gB0 = Bt + (size_t)(bn + rS0) * K + kc;
  const short* gB1 = gB0 + (size_t)16 * K;

  f32x4 acc[4][4];
#pragma unroll
  for (int i = 0; i < 4; ++i)
#pragma unroll
    for (int j = 0; j < 4; ++j) acc[i][j] = (f32x4)(0.f);

  const int fr = lane & 15;
  const int fk = (lane >> 4) * 8;
  const int NT = K / 32;              // 24 or 48 (divisible by 3)

  auto stage = [&](int bi, int k0) {
    load_lds16(gA0 + k0, &As[bi][(size_t)seg0 * 512]);
    load_lds16(gA1 + k0, &As[bi][(size_t)(seg0 + 1) * 512]);
    load_lds16(gB0 + k0, &Bs[bi][(size_t)seg0 * 512]);
    load_lds16(gB1 + k0, &Bs[bi][(size_t)(seg0 + 1) * 512]);
  };
  auto compute = [&](int bi) {
    bf16x8 af[4], bfr[4];
#pragma unroll
    for (int i = 0; i < 4; ++i)
      af[i] = *(const bf16x8*)&As[bi][(size_t)(wm * 64 + i * 16 + fr) * 32 + fk];
#pragma unroll
    for (int j = 0; j < 4; ++j)
      bfr[j] = *(const bf16x8*)&Bs[bi][(size_t)(wn * 64 + j * 16 + fr) * 32 + fk];
#pragma unroll
    for (int i = 0; i < 4; ++i)
#pragma unroll
      for (int j = 0; j < 4; ++j)
        acc[i][j] = __builtin_amdgcn_mfma_f32_16x16x32_bf16(af[i], bfr[j], acc[i][j], 0, 0, 0);
  };

  // prologue: stage tiles 0,1; wait tile 0 (tile 1 stays in flight)
  stage(0, 0);
  stage(1, 32);
  asm volatile("s_waitcnt vmcnt(4)" ::: "memory");
  asm volatile("s_barrier" ::: "memory");

  for (int t = 0; t < NT; t += 3) {
#pragma unroll
    for (int q = 0; q < 3; ++q) {
      const int tt = t + q;                 // tile index; buffer = q (NT%3==0)
      if (tt + 2 < NT) stage((q + 2) % 3, (tt + 2) * 32);
      compute(q);
      if (tt + 1 < NT) {
        if (tt + 2 < NT) asm volatile("s_waitcnt vmcnt(4)" ::: "memory");
        else             asm volatile("s_waitcnt vmcnt(0)" ::: "memory");
        asm volatile("s_barrier" ::: "memory");
      }
    }
  }

  // epilogue: C/D frag mapping col=lane&15, row=(lane>>4)*4+r
  const int orow = (lane >> 4) * 4;
  const int ocol = lane & 15;
#pragma unroll
  for (int i = 0; i < 4; ++i) {
#pragma unroll
    for (int r = 0; r < 4; ++r) {
      const size_t row = (size_t)(bm + wm * 64 + i * 16 + orow + r);
#pragma unroll
      for (int j = 0; j < 4; ++j) {
        const int col = bn + wn * 64 + j * 16 + ocol;
        float v = acc[i][j][r];
        if (MODE == 0) {
          if (col < DI) Pb[row * DI + col] = f2bf(v);
          else          Pb[(size_t)M * DI + row * DI + col - DI] = f2bf(v);
        } else {
          float o = Pf[row * N + col] + v;
          Pf[row * N + col] = o;
          Pb[row * N + col] = f2bf(o);
        }
      }
    }
  }
}

// ---------------- fused causal dwconv(DC=4)+SiLU -> u reduction ----------------
// One block per l; conv output lives only in LDS. xin is bf16.
__global__ __launch_bounds__(256) void conv_u_kernel(const short* __restrict__ xin,  // [B*L, DI] bf16
                                                     const float* __restrict__ cw,   // [DI,4]
                                                     const float* __restrict__ cb,   // [DI]
                                                     const float* __restrict__ A_l,  // [L,DI,DS]
                                                     float* __restrict__ u) {        // [L,B*DS]
  const int l = blockIdx.x;
  __shared__ float smem[B * DI];  // 48 KB: conv output, then reduction buf

  for (int i = threadIdx.x; i < B * (DI / 4); i += 256) {
    const int b = i / (DI / 4);
    const int c = (i % (DI / 4)) * 4;
    float4 q0 = *(const float4*)&cw[(c + 0) * 4];
    float4 q1 = *(const float4*)&cw[(c + 1) * 4];
    float4 q2 = *(const float4*)&cw[(c + 2) * 4];
    float4 q3 = *(const float4*)&cw[(c + 3) * 4];
    float4 acc = *(const float4*)&cb[c];
    const short* xp = xin + (size_t)b * L * DI + c;
#pragma unroll
    for (int k = 0; k < 4; ++k) {
      int lk = l - 3 + k;
      if (lk >= 0) {
        short4 xv = *(const short4*)&xp[(size_t)lk * DI];
        acc.x += (&q0.x)[k] * bf2f(xv.x);
        acc.y += (&q1.x)[k] * bf2f(xv.y);
        acc.z += (&q2.x)[k] * bf2f(xv.z);
        acc.w += (&q3.x)[k] * bf2f(xv.w);
      }
    }
    acc.x = siluf(acc.x); acc.y = siluf(acc.y);
    acc.z = siluf(acc.z); acc.w = siluf(acc.w);
    *(float4*)&smem[b * DI + c] = acc;
  }
  __syncthreads();

  const int s4 = threadIdx.x & 3;    // s quarter
  const int cg = threadIdx.x >> 2;   // 0..63
  const float* Ap = A_l + (size_t)l * DI * DS + s4 * 4;

  float4 acc[B];
#pragma unroll
  for (int b = 0; b < B; ++b) acc[b] = make_float4(0.f, 0.f, 0.f, 0.f);

#pragma unroll 4
  for (int c0 = 0; c0 < DI; c0 += 64) {
    const int c = c0 + cg;
    float4 a4 = *(const float4*)&Ap[(size_t)c * DS];
#pragma unroll
    for (int b = 0; b < B; ++b) {
      float xv = smem[b * DI + c];
      acc[b].x += xv * a4.x; acc[b].y += xv * a4.y;
      acc[b].z += xv * a4.z; acc[b].w += xv * a4.w;
    }
  }

  __syncthreads();  // conv staging consumed; reuse smem as red[128][65]
  float* red = smem;
#pragma unroll
  for (int b = 0; b < B; ++b) {
#pragma unroll
    for (int j = 0; j < 4; ++j) {
      int o = b * 16 + s4 * 4 + j;
      red[o * 65 + cg] = (&acc[b].x)[j];
    }
  }
  __syncthreads();
  if (threadIdx.x < 128) {
    const int o = threadIdx.x;
    float sum = 0.f;
#pragma unroll 8
    for (int g = 0; g < 64; ++g) sum += red[o * 65 + g];
    u[(size_t)l * (B * DS) + o] = INSCALE * sum;
  }
}

// ---------------- truncated-lookback scan ----------------
constexpr int SCAN_CH = 64;
constexpr int SCAN_W  = 320;   // 0.9^320 ~ 2e-15: exact to f32 precision
__global__ void scan_kernel(const float* __restrict__ u, float* __restrict__ hs) {
  const int t  = threadIdx.x;              // 0..127
  const int l1 = blockIdx.x * SCAN_CH;
  int l0 = l1 - SCAN_W; if (l0 < 0) l0 = 0;
  float h = 0.f;
  for (int l = l0; l < l1; ++l)
    h = DECAY * h + u[(size_t)l * (B * DS) + t];
#pragma unroll 4
  for (int l = l1; l < l1 + SCAN_CH; ++l) {
    h = DECAY * h + u[(size_t)l * (B * DS) + t];
    hs[(size_t)l * (B * DS) + t] = h;
  }
}

// ---------------- y[b,l,c] = (sum_s hs[l,b,s]*Bm[l,s,c]) * silu(z) ----------------
__global__ __launch_bounds__(128) void xssm_kernel(const float* __restrict__ hs,   // [L,B*DS]
                                                   const float* __restrict__ B_l,  // [L,DS,DI]
                                                   const short* __restrict__ zb,   // [B*L,DI] bf16
                                                   short* __restrict__ y) {        // [B*L,DI] bf16
  const int l = blockIdx.x;
  const int c = (blockIdx.y * 128 + threadIdx.x) * 4;
  __shared__ float hsl[B * DS];
  if (threadIdx.x < B * DS) hsl[threadIdx.x] = hs[(size_t)l * (B * DS) + threadIdx.x];
  __syncthreads();
  const float* Bp = B_l + (size_t)l * DS * DI + c;

  float4 acc[B];
#pragma unroll
  for (int b = 0; b < B; ++b) acc[b] = make_float4(0.f, 0.f, 0.f, 0.f);
#pragma unroll
  for (int s = 0; s < DS; ++s) {
    float4 bv = *(const float4*)&Bp[(size_t)s * DI];
#pragma unroll
    for (int b = 0; b < B; ++b) {
      float h = hsl[b * DS + s];
      acc[b].x += h * bv.x; acc[b].y += h * bv.y;
      acc[b].z += h * bv.z; acc[b].w += h * bv.w;
    }
  }
#pragma unroll
  for (int b = 0; b < B; ++b) {
    short4 zs = *(const short4*)&zb[((size_t)b * L + l) * DI + c];
    short4 o;
    o.x = f2bf(acc[b].x * siluf(bf2f(zs.x)));
    o.y = f2bf(acc[b].y * siluf(bf2f(zs.y)));
    o.z = f2bf(acc[b].z * siluf(bf2f(zs.z)));
    o.w = f2bf(acc[b].w * siluf(bf2f(zs.w)));
    *(short4*)&y[((size_t)b * L + l) * DI + c] = o;
  }
}

// ---------------- LayerNorm over D ----------------
__global__ __launch_bounds__(256) void ln_kernel(const float* __restrict__ x,
                                                 const float* __restrict__ gam,
                                                 const float* __restrict__ bet,
                                                 float* __restrict__ out) {
  const int row = blockIdx.x;
  const int t = threadIdx.x;
  const float* xr = x + (size_t)row * D;
  float v0 = xr[t], v1 = xr[t + 256], v2 = xr[t + 512];
  float s = v0 + v1 + v2;
  __shared__ float red[4], red2[4];
  const int wid = t >> 6, lane = t & 63;
#pragma unroll
  for (int off = 32; off > 0; off >>= 1) s += __shfl_down(s, off, 64);
  if (lane == 0) red[wid] = s;
  __syncthreads();
  float mu = (red[0] + red[1] + red[2] + red[3]) * (1.0f / D);
  float d0 = v0 - mu, d1 = v1 - mu, d2 = v2 - mu;
  float q = d0 * d0 + d1 * d1 + d2 * d2;
#pragma unroll
  for (int off = 32; off > 0; off >>= 1) q += __shfl_down(q, off, 64);
  if (lane == 0) red2[wid] = q;
  __syncthreads();
  float var = (red2[0] + red2[1] + red2[2] + red2[3]) * (1.0f / D);
  float rstd = rsqrtf(var + LN_EPS);
  size_t base = (size_t)row * D;
  out[base + t]       = d0 * rstd * gam[t]       + bet[t];
  out[base + t + 256] = d1 * rstd * gam[t + 256] + bet[t + 256];
  out[base + t + 512] = d2 * rstd * gam[t + 512] + bet[t + 512];
}

extern "C" void kernel_launch(void* const* d_in, const int* in_sizes, int n_in,
                              void* d_out, int out_size, void* d_ws, size_t ws_size,
                              hipStream_t stream) {
  (void)in_sizes; (void)n_in; (void)out_size; (void)ws_size;
  const float* x   = (const float*)d_in[0];
  const float* Wi  = (const float*)d_in[1];
  const float* cw  = (const float*)d_in[2];
  const float* cb  = (const float*)d_in[3];
  const float* Wo  = (const float*)d_in[4];
  const float* gam = (const float*)d_in[5];
  const float* bet = (const float*)d_in[6];
  const float* Am  = (const float*)d_in[7];
  const float* Bm  = (const float*)d_in[8];
  float* out = (float*)d_out;

  const size_t MN = (size_t)B * L;  // 8192

  float* buf_x  = (float*)d_ws;                          // [MN, D] f32 residual
  short* buf_xb = (short*)(buf_x + MN * D);              // [MN, D] bf16
  short* xin_b  = buf_xb + MN * D;                       // [MN, DI] bf16 (conv input)
  short* zb     = xin_b + MN * DI;                       // [MN, DI] bf16 (gate) — contiguous after xin_b
  short* y_bf   = zb + MN * DI;                          // [MN, DI] bf16
  float* buf_u  = (float*)(y_bf + MN * DI);              // [L, B*DS]
  float* buf_hs = buf_u + (size_t)L * B * DS;            // [L, B*DS]
  short* Wt_i   = (short*)(buf_hs + (size_t)L * B * DS); // [NL, 2*DI, D] bf16
  short* Wt_o   = Wt_i + (size_t)NL * 2 * DI * D;        // [NL, D, DI]  bf16

  {
    int n4 = (int)(MN * D / 4);
    convert_x_kernel<<<(n4 + 255) / 256, 256, 0, stream>>>(x, buf_x, buf_xb, n4);
  }
  transpose_all_kernel<<<dim3(3456, NL), 256, 0, stream>>>(Wi, Wo, Wt_i, Wt_o);

  for (int layer = 0; layer < NL; ++layer) {
    const float* cw_l = cw + (size_t)layer * DI * 4;
    const float* cb_l = cb + (size_t)layer * DI;
    const float* A_l  = Am + (size_t)layer * L * DI * DS;
    const float* B_l  = Bm + (size_t)layer * L * DS * DI;
    const short* Wti_l = Wt_i + (size_t)layer * 2 * DI * D;
    const short* Wto_l = Wt_o + (size_t)layer * D * DI;

    // xz = x @ Wi: both halves bf16 (x_in -> xin_b, z -> zb)
    gemm_bt<0><<<dim3(2 * DI / 128, MN / 128), 256, 0, stream>>>(
        buf_xb, Wti_l, nullptr, xin_b, (int)MN, 2 * DI, D);

    // u = 0.1 * silu(dwconv(xin)) @ A_l   (conv output lives in LDS only)
    conv_u_kernel<<<L, 256, 0, stream>>>(xin_b, cw_l, cb_l, A_l, buf_u);

    // hs = scan(u)
    scan_kernel<<<L / SCAN_CH, B * DS, 0, stream>>>(buf_u, buf_hs);

    // y = (hs @ B_l) * silu(z)  -> bf16
    xssm_kernel<<<dim3(L, 3), 128, 0, stream>>>(buf_hs, B_l, zb, y_bf);

    // x += y @ Wo; also emit bf16 x for next layer
    gemm_bt<1><<<dim3(D / 128, MN / 128), 256, 0, stream>>>(
        y_bf, Wto_l, buf_x, buf_xb, (int)MN, D, DI);
  }

  ln_kernel<<<(int)MN, 256, 0, stream>>>(buf_x, gam, bet, out);
}

// Round 6
// 657.743 us; speedup vs baseline: 1.0676x; 1.0334x over previous
//
#include <hip/hip_runtime.h>
#include <cstddef>
#include <cstdint>

// Problem constants
constexpr int B  = 8;
constexpr int L  = 1024;
constexpr int D  = 768;
constexpr int DI = 1536;
constexpr int DS = 16;
constexpr int NL = 2;
constexpr float DECAY   = 0.9f;
constexpr float INSCALE = 0.1f;
constexpr float LN_EPS  = 1e-5f;

typedef __attribute__((ext_vector_type(8))) short bf16x8;
typedef __attribute__((ext_vector_type(4))) float f32x4;

typedef __attribute__((address_space(3))) uint32_t       lds_u32;
typedef const __attribute__((address_space(1))) uint32_t glb_u32;

__device__ __forceinline__ float siluf(float v) { return v / (1.0f + expf(-v)); }

// f32 -> bf16 (round to nearest even)
__device__ __forceinline__ short f2bf(float f) {
  uint32_t u = __float_as_uint(f);
  u += 0x7fff + ((u >> 16) & 1);
  return (short)(u >> 16);
}
__device__ __forceinline__ float bf2f(short s) {
  return __uint_as_float(((uint32_t)(uint16_t)s) << 16);
}

__device__ __forceinline__ void load_lds16(const short* g, short* l) {
  __builtin_amdgcn_global_load_lds((glb_u32*)g, (lds_u32*)l, 16, 0, 0);
}

// ---------------- convert input x: f32 copy + bf16 copy ----------------
__global__ void convert_x_kernel(const float* __restrict__ x, float* __restrict__ xf,
                                 short* __restrict__ xb, int n4) {
  int i = blockIdx.x * blockDim.x + threadIdx.x;
  if (i >= n4) return;
  float4 v = ((const float4*)x)[i];
  ((float4*)xf)[i] = v;
  short4 s;
  s.x = f2bf(v.x); s.y = f2bf(v.y); s.z = f2bf(v.z); s.w = f2bf(v.w);
  ((short4*)xb)[i] = s;
}

// ---------------- all weight transposes in one launch ----------------
__global__ __launch_bounds__(256) void transpose_all_kernel(const float* __restrict__ Wi,
                                                            const float* __restrict__ Wo,
                                                            short* __restrict__ Wt_i,
                                                            short* __restrict__ Wt_o) {
  __shared__ float t[32][33];
  const int layer = blockIdx.y;
  int bid = blockIdx.x;
  const float* W; short* Wt; int K, N, bx, by;
  if (bid < 2304) {           // Wi tiles: 96 x, 24 y
    W  = Wi  + (size_t)layer * D * 2 * DI;
    Wt = Wt_i + (size_t)layer * 2 * DI * D;
    K = D; N = 2 * DI; bx = bid % 96; by = bid / 96;
  } else {                    // Wo tiles: 24 x, 48 y
    bid -= 2304;
    W  = Wo  + (size_t)layer * DI * D;
    Wt = Wt_o + (size_t)layer * D * DI;
    K = DI; N = D; bx = bid % 24; by = bid / 24;
  }
  const int n0 = bx * 32, k0 = by * 32;
  const int tx = threadIdx.x & 31, ty = threadIdx.x >> 5;
#pragma unroll
  for (int r = ty; r < 32; r += 8) t[r][tx] = W[(size_t)(k0 + r) * N + n0 + tx];
  __syncthreads();
#pragma unroll
  for (int r = ty; r < 32; r += 8) Wt[(size_t)(n0 + r) * K + k0 + tx] = f2bf(t[tx][r]);
}

// ---------------- bf16 MFMA GEMM: C[M,N] = A[M,K] @ Bt[N,K]^T ----------------
// 3-buffer (BK=32) pipeline, ONE barrier + ONE counted vmcnt per K-step.
// LDS tile [128 rows][32 bf16] with T2 XOR swizzle: byte bits[5:4] ^= row bits[2:1].
// global_load_lds writes linearly -> global SOURCE address is pre-permuted per lane
// (involution), ds_read applies the same XOR. Bank-conflict-free frag reads.
// MODE 0: col <  DI -> bf16 Pb[row*DI+col]        (x_in)
//         col >= DI -> bf16 Pb[M*DI + row*DI+col-DI] (z)
// MODE 1: f32 accumulate into Pf[row*N+col], bf16 copy to Pb[row*N+col]
template<int MODE>
__global__ __launch_bounds__(256) void gemm_bt(const short* __restrict__ A,
                                               const short* __restrict__ Bt,
                                               float* __restrict__ Pf,
                                               short* __restrict__ Pb,
                                               int M, int N, int K) {
  __shared__ short As[3][128 * 32];   // 3 x 8 KB
  __shared__ short Bs[3][128 * 32];   // 3 x 8 KB  (48 KB total)
  const int tid  = threadIdx.x;
  const int lane = tid & 63;
  const int w    = tid >> 6;
  const int wm   = w >> 1;
  const int wn   = w & 1;
  const int bm   = blockIdx.y * 128;
  const int bn   = blockIdx.x * 128;

  // staging: wave w stages segments seg0, seg0+1 (16 rows = 1024 B each).
  // physical dest byte P = seg*1024 + lane*16 (hardware: uniform base + lane*16).
  // logical slot Q = P ^ (((P>>7)&3)<<4)  [involution: mask bits live in 7:8]
  //   -> row = Q>>6 (absolute in 0..127), k-chunk g = (Q>>4)&3 (8 bf16 each).
  const int seg0 = w * 2;
  const int lane16 = lane << 4;
  const int P0 = (seg0 << 10) + lane16;
  const int Q0 = P0 ^ (((P0 >> 7) & 3) << 4);
  const int row0 = Q0 >> 6;
  const int g0   = (Q0 >> 4) & 3;
  const int P1 = ((seg0 + 1) << 10) + lane16;
  const int Q1 = P1 ^ (((P1 >> 7) & 3) << 4);
  const int row1 = Q1 >> 6;
  const int g1   = (Q1 >> 4) & 3;

  const short* gA0 = A  + (size_t)(bm + row0) * K + g0 * 8;
  const short* gA1 = A  + (size_t)(bm + row1) * K + g1 * 8;
  const short* gB0 = Bt + (size_t)(bn + row0) * K + g0 * 8;
  const short* gB1 = Bt + (size_t)(bn + row1) * K + g1 * 8;

  f32x4 acc[4][4];
#pragma unroll
  for (int i = 0; i < 4; ++i)
#pragma unroll
    for (int j = 0; j < 4; ++j) acc[i][j] = (f32x4)(0.f);

  const int fr = lane & 15;
  const int h8 = (lane >> 4) << 3;    // k-chunk short offset (0,8,16,24)
  const int NT = K / 32;              // 24 or 48 (divisible by 3)

  auto stage = [&](int bi, int k0) {
    load_lds16(gA0 + k0, &As[bi][(size_t)seg0 * 512]);
    load_lds16(gA1 + k0, &As[bi][(size_t)(seg0 + 1) * 512]);
    load_lds16(gB0 + k0, &Bs[bi][(size_t)seg0 * 512]);
    load_lds16(gB1 + k0, &Bs[bi][(size_t)(seg0 + 1) * 512]);
  };
  auto compute = [&](int bi) {
    bf16x8 af[4], bfr[4];
#pragma unroll
    for (int i = 0; i < 4; ++i) {
      const int r = wm * 64 + i * 16 + fr;
      int si = (r << 5) + h8;
      si ^= ((r >> 1) & 3) << 3;      // same XOR in short units (byte>>1)
      af[i] = *(const bf16x8*)&As[bi][si];
    }
#pragma unroll
    for (int j = 0; j < 4; ++j) {
      const int r = wn * 64 + j * 16 + fr;
      int si = (r << 5) + h8;
      si ^= ((r >> 1) & 3) << 3;
      bfr[j] = *(const bf16x8*)&Bs[bi][si];
    }
#pragma unroll
    for (int i = 0; i < 4; ++i)
#pragma unroll
      for (int j = 0; j < 4; ++j)
        acc[i][j] = __builtin_amdgcn_mfma_f32_16x16x32_bf16(af[i], bfr[j], acc[i][j], 0, 0, 0);
  };

  // prologue: stage tiles 0,1; wait tile 0 (tile 1 stays in flight)
  stage(0, 0);
  stage(1, 32);
  asm volatile("s_waitcnt vmcnt(4)" ::: "memory");
  asm volatile("s_barrier" ::: "memory");

  for (int t = 0; t < NT; t += 3) {
#pragma unroll
    for (int q = 0; q < 3; ++q) {
      const int tt = t + q;                 // tile index; buffer = q (NT%3==0)
      if (tt + 2 < NT) stage((q + 2) % 3, (tt + 2) * 32);
      compute(q);
      if (tt + 1 < NT) {
        if (tt + 2 < NT) asm volatile("s_waitcnt vmcnt(4)" ::: "memory");
        else             asm volatile("s_waitcnt vmcnt(0)" ::: "memory");
        asm volatile("s_barrier" ::: "memory");
      }
    }
  }

  // epilogue: C/D frag mapping col=lane&15, row=(lane>>4)*4+r
  const int orow = (lane >> 4) * 4;
  const int ocol = lane & 15;
#pragma unroll
  for (int i = 0; i < 4; ++i) {
#pragma unroll
    for (int r = 0; r < 4; ++r) {
      const size_t row = (size_t)(bm + wm * 64 + i * 16 + orow + r);
#pragma unroll
      for (int j = 0; j < 4; ++j) {
        const int col = bn + wn * 64 + j * 16 + ocol;
        float v = acc[i][j][r];
        if (MODE == 0) {
          if (col < DI) Pb[row * DI + col] = f2bf(v);
          else          Pb[(size_t)M * DI + row * DI + col - DI] = f2bf(v);
        } else {
          float o = Pf[row * N + col] + v;
          Pf[row * N + col] = o;
          Pb[row * N + col] = f2bf(o);
        }
      }
    }
  }
}

// ---------------- fused causal dwconv(DC=4)+SiLU -> u reduction ----------------
// One block per l; conv output lives only in LDS. xin is bf16.
__global__ __launch_bounds__(256) void conv_u_kernel(const short* __restrict__ xin,  // [B*L, DI] bf16
                                                     const float* __restrict__ cw,   // [DI,4]
                                                     const float* __restrict__ cb,   // [DI]
                                                     const float* __restrict__ A_l,  // [L,DI,DS]
                                                     float* __restrict__ u) {        // [L,B*DS]
  const int l = blockIdx.x;
  __shared__ float smem[B * DI];  // 48 KB: conv output, then reduction buf

  for (int i = threadIdx.x; i < B * (DI / 4); i += 256) {
    const int b = i / (DI / 4);
    const int c = (i % (DI / 4)) * 4;
    float4 q0 = *(const float4*)&cw[(c + 0) * 4];
    float4 q1 = *(const float4*)&cw[(c + 1) * 4];
    float4 q2 = *(const float4*)&cw[(c + 2) * 4];
    float4 q3 = *(const float4*)&cw[(c + 3) * 4];
    float4 acc = *(const float4*)&cb[c];
    const short* xp = xin + (size_t)b * L * DI + c;
#pragma unroll
    for (int k = 0; k < 4; ++k) {
      int lk = l - 3 + k;
      if (lk >= 0) {
        short4 xv = *(const short4*)&xp[(size_t)lk * DI];
        acc.x += (&q0.x)[k] * bf2f(xv.x);
        acc.y += (&q1.x)[k] * bf2f(xv.y);
        acc.z += (&q2.x)[k] * bf2f(xv.z);
        acc.w += (&q3.x)[k] * bf2f(xv.w);
      }
    }
    acc.x = siluf(acc.x); acc.y = siluf(acc.y);
    acc.z = siluf(acc.z); acc.w = siluf(acc.w);
    *(float4*)&smem[b * DI + c] = acc;
  }
  __syncthreads();

  const int s4 = threadIdx.x & 3;    // s quarter
  const int cg = threadIdx.x >> 2;   // 0..63
  const float* Ap = A_l + (size_t)l * DI * DS + s4 * 4;

  float4 acc[B];
#pragma unroll
  for (int b = 0; b < B; ++b) acc[b] = make_float4(0.f, 0.f, 0.f, 0.f);

#pragma unroll 4
  for (int c0 = 0; c0 < DI; c0 += 64) {
    const int c = c0 + cg;
    float4 a4 = *(const float4*)&Ap[(size_t)c * DS];
#pragma unroll
    for (int b = 0; b < B; ++b) {
      float xv = smem[b * DI + c];
      acc[b].x += xv * a4.x; acc[b].y += xv * a4.y;
      acc[b].z += xv * a4.z; acc[b].w += xv * a4.w;
    }
  }

  __syncthreads();  // conv staging consumed; reuse smem as red[128][65]
  float* red = smem;
#pragma unroll
  for (int b = 0; b < B; ++b) {
#pragma unroll
    for (int j = 0; j < 4; ++j) {
      int o = b * 16 + s4 * 4 + j;
      red[o * 65 + cg] = (&acc[b].x)[j];
    }
  }
  __syncthreads();
  if (threadIdx.x < 128) {
    const int o = threadIdx.x;
    float sum = 0.f;
#pragma unroll 8
    for (int g = 0; g < 64; ++g) sum += red[o * 65 + g];
    u[(size_t)l * (B * DS) + o] = INSCALE * sum;
  }
}

// ---------------- fused truncated-lookback scan + xssm ----------------
// Block (lc, third): scans streams for l-chunk [lc*8, lc*8+8) with 320-step
// lookback over L2-resident u (0.9^320 ~ 2e-15, exact in f32), then computes
// y[b,l,c] = (sum_s hs[l,b,s]*Bm[l,s,c]) * silu(z) for its DI/3 column third.
constexpr int XCH    = 8;
constexpr int SCAN_W = 320;
__global__ __launch_bounds__(256) void scan_xssm_kernel(const float* __restrict__ u,    // [L,B*DS]
                                                        const float* __restrict__ B_l,  // [L,DS,DI]
                                                        const short* __restrict__ zb,   // [B*L,DI] bf16
                                                        short* __restrict__ y) {        // [B*L,DI] bf16
  const int l0 = blockIdx.x * XCH;
  const int cb = blockIdx.y * (DI / 3);   // 512 columns per third
  __shared__ float hsl[XCH][B * DS];
  const int t = threadIdx.x;

  if (t < B * DS) {
    int ls = l0 - SCAN_W; if (ls < 0) ls = 0;
    float h = 0.f;
    for (int l = ls; l < l0; ++l) h = DECAY * h + u[(size_t)l * (B * DS) + t];
#pragma unroll
    for (int li = 0; li < XCH; ++li) {
      h = DECAY * h + u[(size_t)(l0 + li) * (B * DS) + t];
      hsl[li][t] = h;
    }
  }
  __syncthreads();

  const int half = t >> 7;        // 0 -> li 0..3, 1 -> li 4..7
  const int tc   = t & 127;
  const int c    = cb + tc * 4;
#pragma unroll
  for (int li2 = 0; li2 < 4; ++li2) {
    const int li = half * 4 + li2;
    const int l  = l0 + li;
    const float* Bp = B_l + (size_t)l * DS * DI + c;
    float4 acc[B];
#pragma unroll
    for (int b = 0; b < B; ++b) acc[b] = make_float4(0.f, 0.f, 0.f, 0.f);
#pragma unroll
    for (int s = 0; s < DS; ++s) {
      float4 bv = *(const float4*)&Bp[(size_t)s * DI];
#pragma unroll
      for (int b = 0; b < B; ++b) {
        float hv = hsl[li][b * DS + s];
        acc[b].x += hv * bv.x; acc[b].y += hv * bv.y;
        acc[b].z += hv * bv.z; acc[b].w += hv * bv.w;
      }
    }
#pragma unroll
    for (int b = 0; b < B; ++b) {
      short4 zs = *(const short4*)&zb[((size_t)b * L + l) * DI + c];
      short4 o;
      o.x = f2bf(acc[b].x * siluf(bf2f(zs.x)));
      o.y = f2bf(acc[b].y * siluf(bf2f(zs.y)));
      o.z = f2bf(acc[b].z * siluf(bf2f(zs.z)));
      o.w = f2bf(acc[b].w * siluf(bf2f(zs.w)));
      *(short4*)&y[((size_t)b * L + l) * DI + c] = o;
    }
  }
}

// ---------------- LayerNorm over D ----------------
__global__ __launch_bounds__(256) void ln_kernel(const float* __restrict__ x,
                                                 const float* __restrict__ gam,
                                                 const float* __restrict__ bet,
                                                 float* __restrict__ out) {
  const int row = blockIdx.x;
  const int t = threadIdx.x;
  const float* xr = x + (size_t)row * D;
  float v0 = xr[t], v1 = xr[t + 256], v2 = xr[t + 512];
  float s = v0 + v1 + v2;
  __shared__ float red[4], red2[4];
  const int wid = t >> 6, lane = t & 63;
#pragma unroll
  for (int off = 32; off > 0; off >>= 1) s += __shfl_down(s, off, 64);
  if (lane == 0) red[wid] = s;
  __syncthreads();
  float mu = (red[0] + red[1] + red[2] + red[3]) * (1.0f / D);
  float d0 = v0 - mu, d1 = v1 - mu, d2 = v2 - mu;
  float q = d0 * d0 + d1 * d1 + d2 * d2;
#pragma unroll
  for (int off = 32; off > 0; off >>= 1) q += __shfl_down(q, off, 64);
  if (lane == 0) red2[wid] = q;
  __syncthreads();
  float var = (red2[0] + red2[1] + red2[2] + red2[3]) * (1.0f / D);
  float rstd = rsqrtf(var + LN_EPS);
  size_t base = (size_t)row * D;
  out[base + t]       = d0 * rstd * gam[t]       + bet[t];
  out[base + t + 256] = d1 * rstd * gam[t + 256] + bet[t + 256];
  out[base + t + 512] = d2 * rstd * gam[t + 512] + bet[t + 512];
}

extern "C" void kernel_launch(void* const* d_in, const int* in_sizes, int n_in,
                              void* d_out, int out_size, void* d_ws, size_t ws_size,
                              hipStream_t stream) {
  (void)in_sizes; (void)n_in; (void)out_size; (void)ws_size;
  const float* x   = (const float*)d_in[0];
  const float* Wi  = (const float*)d_in[1];
  const float* cw  = (const float*)d_in[2];
  const float* cb  = (const float*)d_in[3];
  const float* Wo  = (const float*)d_in[4];
  const float* gam = (const float*)d_in[5];
  const float* bet = (const float*)d_in[6];
  const float* Am  = (const float*)d_in[7];
  const float* Bm  = (const float*)d_in[8];
  float* out = (float*)d_out;

  const size_t MN = (size_t)B * L;  // 8192

  float* buf_x  = (float*)d_ws;                          // [MN, D] f32 residual
  short* buf_xb = (short*)(buf_x + MN * D);              // [MN, D] bf16
  short* xin_b  = buf_xb + MN * D;                       // [MN, DI] bf16 (conv input)
  short* zb     = xin_b + MN * DI;                       // [MN, DI] bf16 (gate)
  short* y_bf   = zb + MN * DI;                          // [MN, DI] bf16
  float* buf_u  = (float*)(y_bf + MN * DI);              // [L, B*DS]
  short* Wt_i   = (short*)(buf_u + (size_t)L * B * DS);  // [NL, 2*DI, D] bf16
  short* Wt_o   = Wt_i + (size_t)NL * 2 * DI * D;        // [NL, D, DI]  bf16

  {
    int n4 = (int)(MN * D / 4);
    convert_x_kernel<<<(n4 + 255) / 256, 256, 0, stream>>>(x, buf_x, buf_xb, n4);
  }
  transpose_all_kernel<<<dim3(3456, NL), 256, 0, stream>>>(Wi, Wo, Wt_i, Wt_o);

  for (int layer = 0; layer < NL; ++layer) {
    const float* cw_l = cw + (size_t)layer * DI * 4;
    const float* cb_l = cb + (size_t)layer * DI;
    const float* A_l  = Am + (size_t)layer * L * DI * DS;
    const float* B_l  = Bm + (size_t)layer * L * DS * DI;
    const short* Wti_l = Wt_i + (size_t)layer * 2 * DI * D;
    const short* Wto_l = Wt_o + (size_t)layer * D * DI;

    // xz = x @ Wi: both halves bf16 (x_in -> xin_b, z -> zb)
    gemm_bt<0><<<dim3(2 * DI / 128, MN / 128), 256, 0, stream>>>(
        buf_xb, Wti_l, nullptr, xin_b, (int)MN, 2 * DI, D);

    // u = 0.1 * silu(dwconv(xin)) @ A_l   (conv output lives in LDS only)
    conv_u_kernel<<<L, 256, 0, stream>>>(xin_b, cw_l, cb_l, A_l, buf_u);

    // hs = scan(u); y = (hs @ B_l) * silu(z)  -> bf16 (fused)
    scan_xssm_kernel<<<dim3(L / XCH, 3), 256, 0, stream>>>(buf_u, B_l, zb, y_bf);

    // x += y @ Wo; also emit bf16 x for next layer
    gemm_bt<1><<<dim3(D / 128, MN / 128), 256, 0, stream>>>(
        y_bf, Wto_l, buf_x, buf_xb, (int)MN, D, DI);
  }

  ln_kernel<<<(int)MN, 256, 0, stream>>>(buf_x, gam, bet, out);
}